// Round 6
// baseline (136.361 us; speedup 1.0000x reference)
//
#include <hip/hip_runtime.h>

// VolumeRenderer R16: 3-step lane segments + coalesced checkpoints.
// R15 counters (first real ones): volrend_scan 46.4us, VALUBusy ~90%,
// FETCH 99.7MB, occupancy 70% => lane=step render is VALU-bound and FAST;
// the serial-chain theory was right. But total regressed (133us): prep's
// tarr stores were uncoalesced (thread=ray writes a 768B private row =>
// 64 scattered 16B stores per wave) and scan fetched 50MB of t's.
// R16:
//  prep: stores t only every 3rd step -> cp[c*B + r], c=0..63: 16.8MB,
//        COALESCED (wave stores 256B runs). Walk still 192 bit-exact steps.
//  render: lane l loads cp_l = t_{3l}, walks ITS 3 steps locally (serial
//        depth 3, adjacent cells => L1-friendly), forms segment (A,T);
//        one 6-step ordered shfl_down reduce with the associative composite
//        (A,T)o(A',T') = (A + T*A', T*T') -- 24 shuffles vs R15's ~39,
//        no per-pass scan serialization, 3x less t-traffic.
// Trajectory (t, idx, delta) bit-identical to reference; only cross-segment
// summation order changes (error << 1/256 quant floor).

constexpr int   R_DIM    = 128;
constexpr int   N_VOX    = R_DIM * R_DIM * R_DIM;
constexpr int   N_STEPS  = 192;
constexpr int   CP_LEN   = 3;                 // steps per lane segment
constexpr int   N_CP     = N_STEPS / CP_LEN;  // 64 = wave size
constexpr float STEP_SZ  = 0.001f;
constexpr float CUBE_SZ  = 1.0f / 128.0f;
constexpr float SIG_MAX  = 5.5f;
constexpr int   PIPE     = 8;
constexpr int   CVT_BLOCKS = (N_VOX / 4 + 255) / 256;   // 2048

__device__ __forceinline__ float sigmoid_fast(float x) {
    return __builtin_amdgcn_rcpf(1.0f + __expf(-x));
}

// One geometric DDA step -> cell coords + exact delta. Bit-identical to the
// reference walk. smin==0 exactly (f in [0,1] -> every per-axis lo <= 0).
__device__ __forceinline__ void geom_step(
    float tl, float tmax,
    float oxR, float oyR, float ozR, float dxR, float dyR, float dzR,
    float ix, float iy, float iz, float ipx, float ipy, float ipz,
    int& i0, int& i1, int& i2, float& d)
{
    float px = __fadd_rn(oxR, __fmul_rn(tl, dxR));
    float py = __fadd_rn(oyR, __fmul_rn(tl, dyR));
    float pz = __fadd_rn(ozR, __fmul_rn(tl, dzR));

    float c0 = fminf(fmaxf(floorf(px), 0.0f), 127.0f);
    float c1 = fminf(fmaxf(floorf(py), 0.0f), 127.0f);
    float c2 = fminf(fmaxf(floorf(pz), 0.0f), 127.0f);
    i0 = (int)c0;
    i1 = (int)c1;
    i2 = (int)c2;

    float t1x = __fmul_rn(__fsub_rn(c0, px), ix);
    float t1y = __fmul_rn(__fsub_rn(c1, py), iy);
    float t1z = __fmul_rn(__fsub_rn(c2, pz), iz);
    float hix = __fadd_rn(t1x, ipx);
    float hiy = __fadd_rn(t1y, ipy);
    float hiz = __fadd_rn(t1z, ipz);
    float smax = fminf(fminf(fminf(hix, hiy), hiz), 1e9f);

    d = __fadd_rn(__fmul_rn(smax, CUBE_SZ), STEP_SZ);
    d = (tl < tmax) ? d : 0.0f;   // inactive -> exact no-op (t frozen)
}

__device__ __forceinline__ void ray_setup(
    const float* __restrict__ origins, const float* __restrict__ dirs, int i,
    float& oxR, float& oyR, float& ozR, float& dxR, float& dyR, float& dzR,
    float& ix, float& iy, float& iz,
    float& ipx, float& ipy, float& ipz,
    float& tmin, float& tmax)
{
    float ox = origins[3 * i + 0];
    float oy = origins[3 * i + 1];
    float oz = origins[3 * i + 2];
    float dx = dirs[3 * i + 0];
    float dy = dirs[3 * i + 1];
    float dz = dirs[3 * i + 2];

    float n2 = __fadd_rn(__fadd_rn(__fmul_rn(dx, dx), __fmul_rn(dy, dy)),
                         __fmul_rn(dz, dz));
    float nrm = sqrtf(n2);
    dx = dx / nrm;
    dy = dy / nrm;
    dz = dz / nrm;

    ix = 1.0f / __fadd_rn(dx, 1e-9f);
    iy = 1.0f / __fadd_rn(dy, 1e-9f);
    iz = 1.0f / __fadd_rn(dz, 1e-9f);

    ipx = fmaxf(ix, 0.0f);
    ipy = fmaxf(iy, 0.0f);
    ipz = fmaxf(iz, 0.0f);

    float t1x = __fmul_rn(-ox, ix), t2x = __fadd_rn(t1x, ix);
    float t1y = __fmul_rn(-oy, iy), t2y = __fadd_rn(t1y, iy);
    float t1z = __fmul_rn(-oz, iz), t2z = __fadd_rn(t1z, iz);
    float lox = fminf(t1x, t2x), hix = fmaxf(t1x, t2x);
    float loy = fminf(t1y, t2y), hiy = fmaxf(t1y, t2y);
    float loz = fminf(t1z, t2z), hiz = fmaxf(t1z, t2z);
    tmin = fmaxf(fmaxf(fmaxf(lox, loy), loz), 0.0f);
    tmax = fminf(fminf(fminf(hix, hiy), hiz), 1e9f);

    // exact *2^7 (scaling lemma keeps the walk bit-identical)
    oxR = __fmul_rn(ox, 128.0f);
    oyR = __fmul_rn(oy, 128.0f);
    ozR = __fmul_rn(oz, 128.0f);
    dxR = __fmul_rn(dx, 128.0f);
    dyR = __fmul_rn(dy, 128.0f);
    dzR = __fmul_rn(dz, 128.0f);
}

__device__ __forceinline__ unsigned pack_voxel(float4 v) {
    unsigned ur = (unsigned)__float2int_rn(sigmoid_fast(v.x) * 255.0f);
    unsigned ug = (unsigned)__float2int_rn(sigmoid_fast(v.y) * 255.0f);
    unsigned ub = (unsigned)__float2int_rn(sigmoid_fast(v.z) * 255.0f);
    unsigned us = (unsigned)__float2int_rn(
        fminf(fmaxf(v.w, 0.0f), SIG_MAX) * (255.0f / SIG_MAX));
    return ur | (ug << 8) | (ub << 16) | (us << 24);
}

// ---- prep: walk blocks (store 64 coalesced checkpoints) + cvt blocks -------
__global__ __launch_bounds__(256) void prep(
    const float4* __restrict__ g, uint4* __restrict__ gq4,
    const float* __restrict__ origins, const float* __restrict__ dirs,
    float* __restrict__ cp, int B, int walk_blocks)
{
    if ((int)blockIdx.x < walk_blocks) {
        int r = blockIdx.x * 256 + threadIdx.x;
        if (r >= B) return;

        float oxR, oyR, ozR, dxR, dyR, dzR, ix, iy, iz, ipx, ipy, ipz;
        float tmin, tmax;
        ray_setup(origins, dirs, r, oxR, oyR, ozR, dxR, dyR, dzR,
                  ix, iy, iz, ipx, ipy, ipz, tmin, tmax);

        float t = tmin;
        for (int c = 0; c < N_CP; ++c) {
            cp[(size_t)c * B + r] = t;     // t_{3c}; wave = 256B coalesced
            #pragma unroll
            for (int p = 0; p < CP_LEN; ++p) {
                int i0, i1, i2; float d;
                geom_step(t, tmax, oxR, oyR, ozR, dxR, dyR, dzR,
                          ix, iy, iz, ipx, ipy, ipz, i0, i1, i2, d);
                t = __fadd_rn(t, d);
            }
            if (__all(t >= tmax)) {        // frozen: remaining cp all = t
                for (int cc = c + 1; cc < N_CP; ++cc)
                    cp[(size_t)cc * B + r] = t;
                break;
            }
        }
        return;
    }

    int tid = (blockIdx.x - walk_blocks) * 256 + threadIdx.x;
    if (tid >= N_VOX / 4) return;
    int zq = tid & 31;              // z-group (4 voxels)
    int y  = (tid >> 5) & 127;
    int x  = tid >> 12;

    int src = (x * R_DIM + y) * R_DIM + 4 * zq;   // float4 index
    float4 v0 = g[src + 0];
    float4 v1 = g[src + 1];
    float4 v2 = g[src + 2];
    float4 v3 = g[src + 3];

    uint4 o;
    o.x = pack_voxel(v0);
    o.y = pack_voxel(v1);
    o.z = pack_voxel(v2);
    o.w = pack_voxel(v3);

    int bid = ((x >> 2) << 10) | ((y >> 2) << 5) | zq;
    int dst = bid * 16 + (x & 3) * 4 + (y & 3);     // uint4 index
    gq4[dst] = o;
}

// ---- render: wave = ray; lane l = steps [3l, 3l+3); ordered pair-reduce ----
__global__ __launch_bounds__(256, 8) void volrend_lane3(
    const unsigned int* __restrict__ gq,   // brick-ordered u8x4, 8.4 MB
    const float* __restrict__ cp,          // checkpoints, 64*B floats
    const float* __restrict__ origins,
    const float* __restrict__ dirs,
    float* __restrict__ out,
    int B)
{
    int lane = threadIdx.x & 63;
    int wid  = threadIdx.x >> 6;
    int r = blockIdx.x * 4 + wid;
    if (r >= B) return;

    float oxR, oyR, ozR, dxR, dyR, dzR, ix, iy, iz, ipx, ipy, ipz, tmin, tmax;
    ray_setup(origins, dirs, r, oxR, oyR, ozR, dxR, dyR, dzR,
              ix, iy, iz, ipx, ipy, ipz, tmin, tmax);
    (void)tmin;

    float t = cp[(size_t)lane * B + r];    // exact t_{3*lane}

    // --- local 3-step segment: (A, T) ---------------------------------
    float light = 1.0f;
    float ar = 0.0f, ag = 0.0f, ab = 0.0f;
    #pragma unroll
    for (int p = 0; p < CP_LEN; ++p) {
        int i0, i1, i2; float d;
        geom_step(t, tmax, oxR, oyR, ozR, dxR, dyR, dzR,
                  ix, iy, iz, ipx, ipy, ipz, i0, i1, i2, d);
        unsigned bid = ((unsigned)(i0 >> 2) << 10) |
                       ((unsigned)(i1 >> 2) << 5) |
                       (unsigned)(i2 >> 2);
        unsigned loc = ((unsigned)(i0 & 3) << 4) |
                       ((unsigned)(i1 & 3) << 2) |
                       (unsigned)(i2 & 3);
        unsigned v = gq[(bid << 6) | loc]; // frozen: d=0 -> a=1 -> neutral
        float sg = (float)(v >> 24);
        float a  = __expf(d * (-SIG_MAX / 255.0f) * sg);
        float w  = light * (1.0f - a) * (1.0f / 255.0f);
        ar = fmaf(w, (float)(v & 255u),         ar);
        ag = fmaf(w, (float)((v >> 8) & 255u),  ag);
        ab = fmaf(w, (float)((v >> 16) & 255u), ab);
        light *= a;
        t = __fadd_rn(t, d);
    }

    // --- ordered tree reduce: (A,T)o(A',T') = (A + T*A', T*T') ---------
    // After step s, lane l holds composite of segments [l, l+2s). Lane 0
    // ends with the full ray. Out-of-range neighbor -> neutral (0,1).
    #pragma unroll
    for (int s = 1; s < 64; s <<= 1) {
        float arn = __shfl_down(ar,    s, 64);
        float agn = __shfl_down(ag,    s, 64);
        float abn = __shfl_down(ab,    s, 64);
        float ltn = __shfl_down(light, s, 64);
        bool ok = (lane + s) < 64;
        arn = ok ? arn : 0.0f;
        agn = ok ? agn : 0.0f;
        abn = ok ? abn : 0.0f;
        ltn = ok ? ltn : 1.0f;
        ar = fmaf(light, arn, ar);
        ag = fmaf(light, agn, ag);
        ab = fmaf(light, abn, ab);
        light *= ltn;
    }

    if (lane == 0) {
        out[3 * r + 0] = ar + light;       // + BACKGROUND * transmittance
        out[3 * r + 1] = ag + light;
        out[3 * r + 2] = ab + light;
    }
}

// ---- fallback: render straight from fp32 grid (if ws too small) ------------
__global__ __launch_bounds__(256) void volrend_f32(
    const float* __restrict__ grid,
    const float* __restrict__ origins,
    const float* __restrict__ dirs,
    float* __restrict__ out,
    int B)
{
    int i = blockIdx.x * blockDim.x + threadIdx.x;
    if (i >= B) return;

    float oxR, oyR, ozR, dxR, dyR, dzR, ix, iy, iz, ipx, ipy, ipz, tmin, tmax;
    ray_setup(origins, dirs, i, oxR, oyR, ozR, dxR, dyR, dzR,
              ix, iy, iz, ipx, ipy, ipz, tmin, tmax);

    const float4* __restrict__ g4 = (const float4*)grid;

    float t = tmin;
    float light = 1.0f;
    float ar = 0.0f, ag = 0.0f, ab = 0.0f;

    for (int chunk = 0; chunk < N_STEPS / PIPE; ++chunk) {
        if (t >= tmax) break;

        float4 val[PIPE];
        float del[PIPE];
        float tl = t;

        #pragma unroll
        for (int p = 0; p < PIPE; ++p) {
            int i0, i1, i2; float d;
            geom_step(tl, tmax, oxR, oyR, ozR, dxR, dyR, dzR,
                      ix, iy, iz, ipx, ipy, ipz, i0, i1, i2, d);
            val[p] = g4[(i0 * R_DIM + i1) * R_DIM + i2];
            del[p] = d;
            tl = __fadd_rn(tl, d);
        }

        #pragma unroll
        for (int p = 0; p < PIPE; ++p) {
            float sigma = fmaxf(val[p].w, 0.0f);
            float att = __expf(-del[p] * sigma);
            float w = light * (1.0f - att);
            ar = fmaf(w, sigmoid_fast(val[p].x), ar);
            ag = fmaf(w, sigmoid_fast(val[p].y), ag);
            ab = fmaf(w, sigmoid_fast(val[p].z), ab);
            light *= att;
        }

        t = tl;
    }

    out[3 * i + 0] = ar + light;
    out[3 * i + 1] = ag + light;
    out[3 * i + 2] = ab + light;
}

extern "C" void kernel_launch(void* const* d_in, const int* in_sizes, int n_in,
                              void* d_out, int out_size, void* d_ws, size_t ws_size,
                              hipStream_t stream) {
    const float* grid    = (const float*)d_in[0];
    const float* origins = (const float*)d_in[1];
    const float* dirs    = (const float*)d_in[2];
    float* out = (float*)d_out;

    int B = in_sizes[1] / 3;

    size_t need = (size_t)N_VOX * 4 + (size_t)N_CP * B * 4; // bricks + cp
    if (ws_size >= need && (B % 64) == 0) {
        uint4* gq4 = (uint4*)d_ws;
        float* cp  = (float*)((char*)d_ws + (size_t)N_VOX * 4);
        int walk_blocks = (B + 255) / 256;
        prep<<<walk_blocks + CVT_BLOCKS, 256, 0, stream>>>(
            (const float4*)grid, gq4, origins, dirs, cp, B, walk_blocks);
        volrend_lane3<<<B / 4, 256, 0, stream>>>(
            (const unsigned int*)gq4, cp, origins, dirs, out, B);
    } else {
        volrend_f32<<<(B + 255) / 256, 256, 0, stream>>>(grid, origins, dirs,
                                                         out, B);
    }
}

// Round 7
// 118.247 us; speedup vs baseline: 1.1532x; 1.1532x over previous
//
#include <hip/hip_runtime.h>

// VolumeRenderer R17: R13 frame + ILP-2 walk.
// Timing model (validated across R12-R16 with fill=46us in-iteration):
//   total = fill(46) + prep(cvt 8 + walk(L)) + seg-render(~30)
//   walk(192 steps) ~ 34us  == ~170 cy/step, 5-7x the static chain model
//   => walk is LATENCY-EXPOSED: 1 wave/SIMD after cvt drains, serial
//   dependent chain, nothing to fill issue gaps.
// R17: interleave TWO independent rays per walk thread (r and r+B/2).
// Per-ray arithmetic order unchanged -> cp bit-identical -> absmax at the
// 1/256 quant floor. Render = R13's checkpoint seg kernel verbatim
// (4 symmetric waves x 48 steps, chunk-break early exit, ~30us).

constexpr int   R_DIM    = 128;
constexpr int   N_VOX    = R_DIM * R_DIM * R_DIM;
constexpr int   N_STEPS  = 192;
constexpr int   NSEG     = 4;
constexpr int   SEG_LEN  = N_STEPS / NSEG;   // 48
constexpr float STEP_SZ  = 0.001f;
constexpr float CUBE_SZ  = 1.0f / 128.0f;
constexpr int   PIPE     = 8;
constexpr float SIG_MAX  = 5.5f;
constexpr int   CVT_BLOCKS = (N_VOX / 4 + 255) / 256;   // 2048

__device__ __forceinline__ float sigmoid_fast(float x) {
    return __builtin_amdgcn_rcpf(1.0f + __expf(-x));
}

// One geometric DDA step -> cell coords + exact delta. Bit-identical to the
// reference walk. smin==0 exactly (f in [0,1] -> every per-axis lo <= 0).
__device__ __forceinline__ void geom_step(
    float tl, float tmax,
    float oxR, float oyR, float ozR, float dxR, float dyR, float dzR,
    float ix, float iy, float iz, float ipx, float ipy, float ipz,
    int& i0, int& i1, int& i2, float& d)
{
    float px = __fadd_rn(oxR, __fmul_rn(tl, dxR));
    float py = __fadd_rn(oyR, __fmul_rn(tl, dyR));
    float pz = __fadd_rn(ozR, __fmul_rn(tl, dzR));

    float c0 = fminf(fmaxf(floorf(px), 0.0f), 127.0f);
    float c1 = fminf(fmaxf(floorf(py), 0.0f), 127.0f);
    float c2 = fminf(fmaxf(floorf(pz), 0.0f), 127.0f);
    i0 = (int)c0;   // dead (DCE'd) in walk-only use
    i1 = (int)c1;
    i2 = (int)c2;

    float t1x = __fmul_rn(__fsub_rn(c0, px), ix);
    float t1y = __fmul_rn(__fsub_rn(c1, py), iy);
    float t1z = __fmul_rn(__fsub_rn(c2, pz), iz);
    float hix = __fadd_rn(t1x, ipx);
    float hiy = __fadd_rn(t1y, ipy);
    float hiz = __fadd_rn(t1z, ipz);
    float smax = fminf(fminf(fminf(hix, hiy), hiz), 1e9f);

    d = __fadd_rn(__fmul_rn(smax, CUBE_SZ), STEP_SZ);
    d = (tl < tmax) ? d : 0.0f;   // inactive -> exact no-op (t frozen)
}

__device__ __forceinline__ void ray_setup(
    const float* __restrict__ origins, const float* __restrict__ dirs, int i,
    float& oxR, float& oyR, float& ozR, float& dxR, float& dyR, float& dzR,
    float& ix, float& iy, float& iz,
    float& ipx, float& ipy, float& ipz,
    float& tmin, float& tmax)
{
    float ox = origins[3 * i + 0];
    float oy = origins[3 * i + 1];
    float oz = origins[3 * i + 2];
    float dx = dirs[3 * i + 0];
    float dy = dirs[3 * i + 1];
    float dz = dirs[3 * i + 2];

    float n2 = __fadd_rn(__fadd_rn(__fmul_rn(dx, dx), __fmul_rn(dy, dy)),
                         __fmul_rn(dz, dz));
    float nrm = sqrtf(n2);
    dx = dx / nrm;
    dy = dy / nrm;
    dz = dz / nrm;

    ix = 1.0f / __fadd_rn(dx, 1e-9f);
    iy = 1.0f / __fadd_rn(dy, 1e-9f);
    iz = 1.0f / __fadd_rn(dz, 1e-9f);

    ipx = fmaxf(ix, 0.0f);
    ipy = fmaxf(iy, 0.0f);
    ipz = fmaxf(iz, 0.0f);

    float t1x = __fmul_rn(-ox, ix), t2x = __fadd_rn(t1x, ix);
    float t1y = __fmul_rn(-oy, iy), t2y = __fadd_rn(t1y, iy);
    float t1z = __fmul_rn(-oz, iz), t2z = __fadd_rn(t1z, iz);
    float lox = fminf(t1x, t2x), hix = fmaxf(t1x, t2x);
    float loy = fminf(t1y, t2y), hiy = fmaxf(t1y, t2y);
    float loz = fminf(t1z, t2z), hiz = fmaxf(t1z, t2z);
    tmin = fmaxf(fmaxf(fmaxf(lox, loy), loz), 0.0f);
    tmax = fminf(fminf(fminf(hix, hiy), hiz), 1e9f);

    // exact *2^7 (scaling lemma keeps the walk bit-identical)
    oxR = __fmul_rn(ox, 128.0f);
    oyR = __fmul_rn(oy, 128.0f);
    ozR = __fmul_rn(oz, 128.0f);
    dxR = __fmul_rn(dx, 128.0f);
    dyR = __fmul_rn(dy, 128.0f);
    dzR = __fmul_rn(dz, 128.0f);
}

__device__ __forceinline__ unsigned pack_voxel(float4 v) {
    unsigned ur = (unsigned)__float2int_rn(sigmoid_fast(v.x) * 255.0f);
    unsigned ug = (unsigned)__float2int_rn(sigmoid_fast(v.y) * 255.0f);
    unsigned ub = (unsigned)__float2int_rn(sigmoid_fast(v.z) * 255.0f);
    unsigned us = (unsigned)__float2int_rn(
        fminf(fmaxf(v.w, 0.0f), SIG_MAX) * (255.0f / SIG_MAX));
    return ur | (ug << 8) | (ub << 16) | (us << 24);
}

// ---- prep: ILP-2 walk blocks + cvt blocks, one launch ----------------------
// walk: thread = TWO rays (r, r+B/2), chains interleaved by the compiler ->
//       halves exposed dependent-op latency. 3x48 bit-exact steps each,
//       cp = t48/t96/t144 per ray (coalesced 256B runs).
// cvt : thread = 4 z-voxels -> brick-ordered u8x4 (as R11+).
__global__ __launch_bounds__(256) void prep(
    const float4* __restrict__ g, uint4* __restrict__ gq4,
    const float* __restrict__ origins, const float* __restrict__ dirs,
    float* __restrict__ cp, int B, int walk_blocks)
{
    if ((int)blockIdx.x < walk_blocks) {
        int half = B >> 1;
        int r0 = blockIdx.x * 256 + threadIdx.x;
        if (r0 >= half) return;
        int r1 = r0 + half;

        float oxa, oya, oza, dxa, dya, dza, ixa, iya, iza, pxa, pya, pza;
        float tmina, tmaxa;
        ray_setup(origins, dirs, r0, oxa, oya, oza, dxa, dya, dza,
                  ixa, iya, iza, pxa, pya, pza, tmina, tmaxa);
        float oxb, oyb, ozb, dxb, dyb, dzb, ixb, iyb, izb, pxb, pyb, pzb;
        float tminb, tmaxb;
        ray_setup(origins, dirs, r1, oxb, oyb, ozb, dxb, dyb, dzb,
                  ixb, iyb, izb, pxb, pyb, pzb, tminb, tmaxb);

        float ta = tmina, tb = tminb;
        #pragma unroll
        for (int s = 1; s < NSEG; ++s) {
            for (int c = 0; c < SEG_LEN / PIPE; ++c) {
                if (ta >= tmaxa && tb >= tmaxb) break;
                #pragma unroll
                for (int p = 0; p < PIPE; ++p) {
                    int i0, i1, i2; float da, db;
                    geom_step(ta, tmaxa, oxa, oya, oza, dxa, dya, dza,
                              ixa, iya, iza, pxa, pya, pza, i0, i1, i2, da);
                    geom_step(tb, tmaxb, oxb, oyb, ozb, dxb, dyb, dzb,
                              ixb, iyb, izb, pxb, pyb, pzb, i0, i1, i2, db);
                    ta = __fadd_rn(ta, da);
                    tb = __fadd_rn(tb, db);
                }
            }
            cp[(s - 1) * B + r0] = ta;
            cp[(s - 1) * B + r1] = tb;
        }
        return;
    }

    int tid = (blockIdx.x - walk_blocks) * 256 + threadIdx.x;
    if (tid >= N_VOX / 4) return;
    int zq = tid & 31;              // z-group (4 voxels)
    int y  = (tid >> 5) & 127;
    int x  = tid >> 12;

    int src = (x * R_DIM + y) * R_DIM + 4 * zq;   // float4 index
    float4 v0 = g[src + 0];
    float4 v1 = g[src + 1];
    float4 v2 = g[src + 2];
    float4 v3 = g[src + 3];

    uint4 o;
    o.x = pack_voxel(v0);
    o.y = pack_voxel(v1);
    o.z = pack_voxel(v2);
    o.w = pack_voxel(v3);

    // brick-ordered destination: bid = bx<<10|by<<5|bz, loc = lx<<4|ly<<2|lz
    int bid = ((x >> 2) << 10) | ((y >> 2) << 5) | zq;
    int dst = bid * 16 + (x & 3) * 4 + (y & 3);     // uint4 index
    gq4[dst] = o;
}

// ---- render: 4 symmetric waves/block; wave s renders steps [s*48,s*48+48) --
__global__ __launch_bounds__(256) void volrend_seg(
    const unsigned int* __restrict__ gq,   // brick-ordered u8x4, 8.4 MB
    const float* __restrict__ cp,          // t checkpoints, 3*B floats
    const float* __restrict__ origins,
    const float* __restrict__ dirs,
    float* __restrict__ out,
    int B)
{
    __shared__ float4 lds[64 * (NSEG - 1)];

    int lane = threadIdx.x & 63;
    int seg  = threadIdx.x >> 6;
    int i = blockIdx.x * 64 + lane;

    float oxR, oyR, ozR, dxR, dyR, dzR, ix, iy, iz, ipx, ipy, ipz, tmin, tmax;
    ray_setup(origins, dirs, i, oxR, oyR, ozR, dxR, dyR, dzR,
              ix, iy, iz, ipx, ipy, ipz, tmin, tmax);

    // checkpointed start: no prewalk, waves symmetric
    float t = (seg == 0) ? tmin : cp[(seg - 1) * B + i];

    float light = 1.0f;
    float ar = 0.0f, ag = 0.0f, ab = 0.0f;

    for (int chunk = 0; chunk < SEG_LEN / PIPE; ++chunk) {
        if (t >= tmax) break;

        unsigned int val[PIPE];
        float del[PIPE];
        float tl = t;

        #pragma unroll
        for (int p = 0; p < PIPE; ++p) {
            int i0, i1, i2; float d;
            geom_step(tl, tmax, oxR, oyR, ozR, dxR, dyR, dzR,
                      ix, iy, iz, ipx, ipy, ipz, i0, i1, i2, d);
            unsigned bid = ((unsigned)(i0 >> 2) << 10) |
                           ((unsigned)(i1 >> 2) << 5) |
                           (unsigned)(i2 >> 2);
            unsigned loc = ((unsigned)(i0 & 3) << 4) |
                           ((unsigned)(i1 & 3) << 2) |
                           (unsigned)(i2 & 3);
            val[p] = gq[(bid << 6) | loc];   // dead voxel: sigma-u8==0 -> att=1
            del[p] = d;
            tl = __fadd_rn(tl, d);
        }

        #pragma unroll
        for (int p = 0; p < PIPE; ++p) {
            unsigned int v = val[p];
            // byte-extract casts compile to v_cvt_f32_ubyte0..3
            float r  = (float)(v & 255u);
            float gg = (float)((v >> 8) & 255u);
            float b  = (float)((v >> 16) & 255u);
            float sg = (float)(v >> 24);
            float att = __expf(del[p] * (-SIG_MAX / 255.0f) * sg);
            float w  = light * (1.0f - att);
            float ws = w * (1.0f / 255.0f);
            ar = fmaf(ws, r, ar);
            ag = fmaf(ws, gg, ag);
            ab = fmaf(ws, b, ab);
            light *= att;
        }

        t = tl;
    }

    // --- compose: out = A0 + L0*(A1 + L1*(A2 + L2*(A3 + L3))) --------------
    if (seg > 0) {
        lds[(seg - 1) * 64 + lane] = make_float4(ar, ag, ab, light);
    }
    __syncthreads();
    if (seg == 0) {
        float4 s1 = lds[0 * 64 + lane];
        float4 s2 = lds[1 * 64 + lane];
        float4 s3 = lds[2 * 64 + lane];
        float r3 = s3.x + s3.w, g3 = s3.y + s3.w, b3 = s3.z + s3.w;
        float r2 = fmaf(s2.w, r3, s2.x);
        float g2 = fmaf(s2.w, g3, s2.y);
        float b2 = fmaf(s2.w, b3, s2.z);
        float r1 = fmaf(s1.w, r2, s1.x);
        float g1 = fmaf(s1.w, g2, s1.y);
        float b1 = fmaf(s1.w, b2, s1.z);
        out[3 * i + 0] = fmaf(light, r1, ar);
        out[3 * i + 1] = fmaf(light, g1, ag);
        out[3 * i + 2] = fmaf(light, b1, ab);
    }
}

// ---- fallback: render straight from fp32 grid (if ws too small) ------------
__global__ __launch_bounds__(256) void volrend_f32(
    const float* __restrict__ grid,
    const float* __restrict__ origins,
    const float* __restrict__ dirs,
    float* __restrict__ out,
    int B)
{
    int i = blockIdx.x * blockDim.x + threadIdx.x;
    if (i >= B) return;

    float oxR, oyR, ozR, dxR, dyR, dzR, ix, iy, iz, ipx, ipy, ipz, tmin, tmax;
    ray_setup(origins, dirs, i, oxR, oyR, ozR, dxR, dyR, dzR,
              ix, iy, iz, ipx, ipy, ipz, tmin, tmax);

    const float4* __restrict__ g4 = (const float4*)grid;

    float t = tmin;
    float light = 1.0f;
    float ar = 0.0f, ag = 0.0f, ab = 0.0f;

    for (int chunk = 0; chunk < N_STEPS / PIPE; ++chunk) {
        if (t >= tmax) break;

        float4 val[PIPE];
        float del[PIPE];
        float tl = t;

        #pragma unroll
        for (int p = 0; p < PIPE; ++p) {
            int i0, i1, i2; float d;
            geom_step(tl, tmax, oxR, oyR, ozR, dxR, dyR, dzR,
                      ix, iy, iz, ipx, ipy, ipz, i0, i1, i2, d);
            val[p] = g4[(i0 * R_DIM + i1) * R_DIM + i2];
            del[p] = d;
            tl = __fadd_rn(tl, d);
        }

        #pragma unroll
        for (int p = 0; p < PIPE; ++p) {
            float sigma = fmaxf(val[p].w, 0.0f);
            float att = __expf(-del[p] * sigma);
            float w = light * (1.0f - att);
            ar = fmaf(w, sigmoid_fast(val[p].x), ar);
            ag = fmaf(w, sigmoid_fast(val[p].y), ag);
            ab = fmaf(w, sigmoid_fast(val[p].z), ab);
            light *= att;
        }

        t = tl;
    }

    out[3 * i + 0] = ar + light;
    out[3 * i + 1] = ag + light;
    out[3 * i + 2] = ab + light;
}

extern "C" void kernel_launch(void* const* d_in, const int* in_sizes, int n_in,
                              void* d_out, int out_size, void* d_ws, size_t ws_size,
                              hipStream_t stream) {
    const float* grid    = (const float*)d_in[0];
    const float* origins = (const float*)d_in[1];
    const float* dirs    = (const float*)d_in[2];
    float* out = (float*)d_out;

    int B = in_sizes[1] / 3;

    size_t need = (size_t)N_VOX * 4 + (size_t)(NSEG - 1) * B * 4;
    if (ws_size >= need && (B % 128) == 0) {
        uint4* gq4 = (uint4*)d_ws;
        float* cp  = (float*)((char*)d_ws + (size_t)N_VOX * 4);
        int walk_blocks = (B / 2 + 255) / 256;
        prep<<<walk_blocks + CVT_BLOCKS, 256, 0, stream>>>(
            (const float4*)grid, gq4, origins, dirs, cp, B, walk_blocks);
        volrend_seg<<<B / 64, 64 * NSEG, 0, stream>>>(
            (const unsigned int*)gq4, cp, origins, dirs, out, B);
    } else {
        volrend_f32<<<(B + 255) / 256, 256, 0, stream>>>(grid, origins, dirs,
                                                         out, B);
    }
}